// Round 4
// baseline (64.346 us; speedup 1.0000x reference)
//
#include <hip/hip_runtime.h>

#define BLK 256
#define NBLOCKS 3584   // 2048 (scale0) + 1024 (scale1) + 512 (scale2)

// Flat-grid scale decompose: block b ->
//   scale0: b in [0,2048)    n4=524288  sh=16
//   scale1: b in [2048,3072) n4=262144  sh=15
//   scale2: b in [3072,3584) n4=131072  sh=14
// tid = (b - base)*BLK + threadIdx.x  = float4 index within the scale.

// ---------------------------------------------------------------------------
// Distance kernel, f-reuse, ILP-forced: issue 1 f-load + 10 M-loads into
// NAMED registers, then sched_barrier(0) so the scheduler cannot sink the
// loads into the compute (keeps ~11 VMEM ops in flight per thread).
// Also writes the feature into CI's first half. Deterministic per-block
// partials: partials[item*NBLOCKS + b].
// ---------------------------------------------------------------------------
__global__ __launch_bounds__(BLK) void
dist_kernel(const float* __restrict__ f1, const float* __restrict__ M1,
            const float* __restrict__ f2, const float* __restrict__ M2,
            const float* __restrict__ f3, const float* __restrict__ M3,
            float* __restrict__ out, float* __restrict__ partials) {
    const int b = blockIdx.x;
    const float* f; const float* M; int n4, sh, lb; float* CI;
    if (b < 2048)      { f = f1; M = M1; n4 = 524288; sh = 16; lb = b;        CI = out;           }
    else if (b < 3072) { f = f2; M = M2; n4 = 262144; sh = 15; lb = b - 2048; CI = out + 4194304; }
    else               { f = f3; M = M3; n4 = 131072; sh = 14; lb = b - 3072; CI = out + 6291456; }
    const int tid = lb * BLK + threadIdx.x;

    const float4* __restrict__ f4 = (const float4*)f;
    const float4* __restrict__ m4 = (const float4*)M;

    // ---- load cluster: 11 independent VMEM ops, all issued before any use.
    float4 a  = f4[tid];
    float4 m0 = m4[tid];
    float4 m1 = m4[(size_t)1 * n4 + tid];
    float4 m2 = m4[(size_t)2 * n4 + tid];
    float4 m3 = m4[(size_t)3 * n4 + tid];
    float4 m4v = m4[(size_t)4 * n4 + tid];
    float4 m5 = m4[(size_t)5 * n4 + tid];
    float4 m6 = m4[(size_t)6 * n4 + tid];
    float4 m7 = m4[(size_t)7 * n4 + tid];
    float4 m8 = m4[(size_t)8 * n4 + tid];
    float4 m9 = m4[(size_t)9 * n4 + tid];
    __builtin_amdgcn_sched_barrier(0);   // nothing moves across: loads stay up

    // Feature -> CI first half (store; doesn't stall the M loads).
    {
        const int bi = tid >> sh, r = tid & ((1 << sh) - 1);
        ((float4*)CI)[((size_t)bi << (sh + 1)) + r] = a;
    }

    float acc[10];
    {
        float dx, dy, dz, dw;
        dx = a.x - m0.x;  dy = a.y - m0.y;  dz = a.z - m0.z;  dw = a.w - m0.w;
        acc[0] = dx * dx + dy * dy + dz * dz + dw * dw;
        dx = a.x - m1.x;  dy = a.y - m1.y;  dz = a.z - m1.z;  dw = a.w - m1.w;
        acc[1] = dx * dx + dy * dy + dz * dz + dw * dw;
        dx = a.x - m2.x;  dy = a.y - m2.y;  dz = a.z - m2.z;  dw = a.w - m2.w;
        acc[2] = dx * dx + dy * dy + dz * dz + dw * dw;
        dx = a.x - m3.x;  dy = a.y - m3.y;  dz = a.z - m3.z;  dw = a.w - m3.w;
        acc[3] = dx * dx + dy * dy + dz * dz + dw * dw;
        dx = a.x - m4v.x; dy = a.y - m4v.y; dz = a.z - m4v.z; dw = a.w - m4v.w;
        acc[4] = dx * dx + dy * dy + dz * dz + dw * dw;
        dx = a.x - m5.x;  dy = a.y - m5.y;  dz = a.z - m5.z;  dw = a.w - m5.w;
        acc[5] = dx * dx + dy * dy + dz * dz + dw * dw;
        dx = a.x - m6.x;  dy = a.y - m6.y;  dz = a.z - m6.z;  dw = a.w - m6.w;
        acc[6] = dx * dx + dy * dy + dz * dz + dw * dw;
        dx = a.x - m7.x;  dy = a.y - m7.y;  dz = a.z - m7.z;  dw = a.w - m7.w;
        acc[7] = dx * dx + dy * dy + dz * dz + dw * dw;
        dx = a.x - m8.x;  dy = a.y - m8.y;  dz = a.z - m8.z;  dw = a.w - m8.w;
        acc[8] = dx * dx + dy * dy + dz * dz + dw * dw;
        dx = a.x - m9.x;  dy = a.y - m9.y;  dz = a.z - m9.z;  dw = a.w - m9.w;
        acc[9] = dx * dx + dy * dy + dz * dz + dw * dw;
    }

    __shared__ float s[10][4];
    #pragma unroll
    for (int i = 0; i < 10; ++i) {
        float v = acc[i];
        #pragma unroll
        for (int off = 32; off > 0; off >>= 1) v += __shfl_down(v, off);
        if ((threadIdx.x & 63) == 0) s[i][threadIdx.x >> 6] = v;
    }
    __syncthreads();
    if (threadIdx.x < 10)
        partials[threadIdx.x * NBLOCKS + b] =
            s[threadIdx.x][0] + s[threadIdx.x][1] + s[threadIdx.x][2] + s[threadIdx.x][3];
}

// ---------------------------------------------------------------------------
// Reduce partials per (item, scale), then argmin over
// sqrt(s0)+sqrt(s1)+sqrt(s2). 1 block x 1024 threads; wave w (<10) owns
// item w and keeps the three scale ranges separate while summing.
// ---------------------------------------------------------------------------
__global__ void reduce_argmin_kernel(const float* __restrict__ partials,
                                     int* __restrict__ idx_out) {
    __shared__ float tot[10];
    const int wv = threadIdx.x >> 6, lane = threadIdx.x & 63;
    if (wv < 10) {
        const float* p = partials + wv * NBLOCKS;
        float s0 = 0.f, s1 = 0.f, s2 = 0.f;
        for (int i = lane; i < 2048; i += 64) s0 += p[i];
        for (int i = 2048 + lane; i < 3072; i += 64) s1 += p[i];
        for (int i = 3072 + lane; i < 3584; i += 64) s2 += p[i];
        #pragma unroll
        for (int off = 32; off > 0; off >>= 1) {
            s0 += __shfl_down(s0, off);
            s1 += __shfl_down(s1, off);
            s2 += __shfl_down(s2, off);
        }
        if (lane == 0) tot[wv] = sqrtf(s0) + sqrtf(s1) + sqrtf(s2);
    }
    __syncthreads();
    if (threadIdx.x == 0) {
        float best = 3.4e38f; int bi = 0;
        for (int i = 0; i < 10; ++i) {
            float t = tot[i];
            if (t < best) { best = t; bi = i; }
        }
        *idx_out = bi;
    }
}

// ---------------------------------------------------------------------------
// Gather: M[idx] float4 -> CI second half + mi. (Feature half already done.)
// ---------------------------------------------------------------------------
__global__ void gather_kernel(const float* __restrict__ M1, const float* __restrict__ M2,
                              const float* __restrict__ M3, const int* __restrict__ idx_ptr,
                              float* __restrict__ out) {
    const int b = blockIdx.x;
    const float* M; int n4, sh, lb; float* CI; float* mi;
    if (b < 2048)      { M = M1; n4 = 524288; sh = 16; lb = b;        CI = out;           mi = out + 7340032;  }
    else if (b < 3072) { M = M2; n4 = 262144; sh = 15; lb = b - 2048; CI = out + 4194304; mi = out + 9437184;  }
    else               { M = M3; n4 = 131072; sh = 14; lb = b - 3072; CI = out + 6291456; mi = out + 10485760; }
    const int tid = lb * BLK + threadIdx.x;
    const int idx = *idx_ptr;

    float4 v = ((const float4*)M)[(size_t)idx * n4 + tid];
    const int bi = tid >> sh, r = tid & ((1 << sh) - 1);
    const int S4 = 1 << sh;
    ((float4*)CI)[((size_t)bi << (sh + 1)) + S4 + r] = v;
    ((float4*)mi)[tid] = v;
}

extern "C" void kernel_launch(void* const* d_in, const int* in_sizes, int n_in,
                              void* d_out, int out_size, void* d_ws, size_t ws_size,
                              hipStream_t stream) {
    const float* f1 = (const float*)d_in[0];
    const float* f2 = (const float*)d_in[1];
    const float* f3 = (const float*)d_in[2];
    const float* M1 = (const float*)d_in[3];
    const float* M2 = (const float*)d_in[4];
    const float* M3 = (const float*)d_in[5];
    float* out = (float*)d_out;

    // Output flat layout (fp32 elements):
    //   CI1 @ 0         4194304 | CI2 @ 4194304  2097152 | CI3 @ 6291456  1048576
    //   mi1 @ 7340032   2097152 | mi2 @ 9437184  1048576 | mi3 @ 10485760  524288
    // Scratch: partials (10*NBLOCKS fp32 = 143 KB) in the mi3 region (fully
    // overwritten by gather afterwards). idx in d_ws.
    float* partials = out + 10485760;
    int* idxp = (int*)d_ws;

    dist_kernel<<<NBLOCKS, BLK, 0, stream>>>(f1, M1, f2, M2, f3, M3, out, partials);
    reduce_argmin_kernel<<<1, 1024, 0, stream>>>(partials, idxp);
    gather_kernel<<<NBLOCKS, BLK, 0, stream>>>(M1, M2, M3, idxp, out);
}

// Round 5
// 63.520 us; speedup vs baseline: 1.0130x; 1.0130x over previous
//
#include <hip/hip_runtime.h>

#define BLK 256
#define NBLOCKS 3584   // 2048 (scale0) + 1024 (scale1) + 512 (scale2)

// Flat-grid scale decompose: block b ->
//   scale0: b in [0,2048)    n4=524288  sh=16
//   scale1: b in [2048,3072) n4=262144  sh=15
//   scale2: b in [3072,3584) n4=131072  sh=14
// tid = (b - base)*BLK + threadIdx.x  = float4 index within the scale.

// ---------------------------------------------------------------------------
// Distance kernel, f-reuse, MLP forced via ONE atomic inline-asm block:
// 11 global_load_dwordx4 (f + 10 M items) issued back-to-back into 44
// distinct VGPRs, one s_waitcnt vmcnt(0) at the end. The compiler cannot
// split, sink, or serialize it. voffset is a single VGPR walked by an SGPR
// stride between issues (address is latched at issue -> reuse is safe).
// Also writes the feature into CI's first half. Deterministic per-block
// partials: partials[item*NBLOCKS + b].
// ---------------------------------------------------------------------------
__global__ __launch_bounds__(BLK) void
dist_kernel(const float* __restrict__ f1, const float* __restrict__ M1,
            const float* __restrict__ f2, const float* __restrict__ M2,
            const float* __restrict__ f3, const float* __restrict__ M3,
            float* __restrict__ out, float* __restrict__ partials) {
    const int b = blockIdx.x;
    const float* f; const float* M; int n4, sh, lb; float* CI;
    if (b < 2048)      { f = f1; M = M1; n4 = 524288; sh = 16; lb = b;        CI = out;           }
    else if (b < 3072) { f = f2; M = M2; n4 = 262144; sh = 15; lb = b - 2048; CI = out + 4194304; }
    else               { f = f3; M = M3; n4 = 131072; sh = 14; lb = b - 3072; CI = out + 6291456; }
    const int tid = lb * BLK + threadIdx.x;

    unsigned voff = (unsigned)tid * 16u;                 // byte offset of this thread's float4
    const unsigned sstride = (unsigned)n4 * 16u;         // bytes per memory item
    const unsigned long long fbase = (unsigned long long)f;
    const unsigned long long mbase = (unsigned long long)M;

    float4 a, m0, m1, m2, m3, m4v, m5, m6, m7, m8, m9;
    asm volatile(
        "global_load_dwordx4 %[va], %[off], %[fb]\n\t"
        "global_load_dwordx4 %[v0], %[off], %[mb]\n\t"
        "v_add_u32 %[off], %[st], %[off]\n\t"
        "global_load_dwordx4 %[v1], %[off], %[mb]\n\t"
        "v_add_u32 %[off], %[st], %[off]\n\t"
        "global_load_dwordx4 %[v2], %[off], %[mb]\n\t"
        "v_add_u32 %[off], %[st], %[off]\n\t"
        "global_load_dwordx4 %[v3], %[off], %[mb]\n\t"
        "v_add_u32 %[off], %[st], %[off]\n\t"
        "global_load_dwordx4 %[v4], %[off], %[mb]\n\t"
        "v_add_u32 %[off], %[st], %[off]\n\t"
        "global_load_dwordx4 %[v5], %[off], %[mb]\n\t"
        "v_add_u32 %[off], %[st], %[off]\n\t"
        "global_load_dwordx4 %[v6], %[off], %[mb]\n\t"
        "v_add_u32 %[off], %[st], %[off]\n\t"
        "global_load_dwordx4 %[v7], %[off], %[mb]\n\t"
        "v_add_u32 %[off], %[st], %[off]\n\t"
        "global_load_dwordx4 %[v8], %[off], %[mb]\n\t"
        "v_add_u32 %[off], %[st], %[off]\n\t"
        "global_load_dwordx4 %[v9], %[off], %[mb]\n\t"
        "s_waitcnt vmcnt(0)"
        : [va]"=&v"(a),  [v0]"=&v"(m0), [v1]"=&v"(m1), [v2]"=&v"(m2),
          [v3]"=&v"(m3), [v4]"=&v"(m4v),[v5]"=&v"(m5), [v6]"=&v"(m6),
          [v7]"=&v"(m7), [v8]"=&v"(m8), [v9]"=&v"(m9), [off]"+v"(voff)
        : [st]"s"(sstride), [fb]"s"(fbase), [mb]"s"(mbase)
    );

    // Feature -> CI first half (f already in registers).
    {
        const int bi = tid >> sh, r = tid & ((1 << sh) - 1);
        ((float4*)CI)[((size_t)bi << (sh + 1)) + r] = a;
    }

    float acc[10];
    {
        float dx, dy, dz, dw;
        dx = a.x - m0.x;  dy = a.y - m0.y;  dz = a.z - m0.z;  dw = a.w - m0.w;
        acc[0] = dx * dx + dy * dy + dz * dz + dw * dw;
        dx = a.x - m1.x;  dy = a.y - m1.y;  dz = a.z - m1.z;  dw = a.w - m1.w;
        acc[1] = dx * dx + dy * dy + dz * dz + dw * dw;
        dx = a.x - m2.x;  dy = a.y - m2.y;  dz = a.z - m2.z;  dw = a.w - m2.w;
        acc[2] = dx * dx + dy * dy + dz * dz + dw * dw;
        dx = a.x - m3.x;  dy = a.y - m3.y;  dz = a.z - m3.z;  dw = a.w - m3.w;
        acc[3] = dx * dx + dy * dy + dz * dz + dw * dw;
        dx = a.x - m4v.x; dy = a.y - m4v.y; dz = a.z - m4v.z; dw = a.w - m4v.w;
        acc[4] = dx * dx + dy * dy + dz * dz + dw * dw;
        dx = a.x - m5.x;  dy = a.y - m5.y;  dz = a.z - m5.z;  dw = a.w - m5.w;
        acc[5] = dx * dx + dy * dy + dz * dz + dw * dw;
        dx = a.x - m6.x;  dy = a.y - m6.y;  dz = a.z - m6.z;  dw = a.w - m6.w;
        acc[6] = dx * dx + dy * dy + dz * dz + dw * dw;
        dx = a.x - m7.x;  dy = a.y - m7.y;  dz = a.z - m7.z;  dw = a.w - m7.w;
        acc[7] = dx * dx + dy * dy + dz * dz + dw * dw;
        dx = a.x - m8.x;  dy = a.y - m8.y;  dz = a.z - m8.z;  dw = a.w - m8.w;
        acc[8] = dx * dx + dy * dy + dz * dz + dw * dw;
        dx = a.x - m9.x;  dy = a.y - m9.y;  dz = a.z - m9.z;  dw = a.w - m9.w;
        acc[9] = dx * dx + dy * dy + dz * dz + dw * dw;
    }

    __shared__ float s[10][4];
    #pragma unroll
    for (int i = 0; i < 10; ++i) {
        float v = acc[i];
        #pragma unroll
        for (int off = 32; off > 0; off >>= 1) v += __shfl_down(v, off);
        if ((threadIdx.x & 63) == 0) s[i][threadIdx.x >> 6] = v;
    }
    __syncthreads();
    if (threadIdx.x < 10)
        partials[threadIdx.x * NBLOCKS + b] =
            s[threadIdx.x][0] + s[threadIdx.x][1] + s[threadIdx.x][2] + s[threadIdx.x][3];
}

// ---------------------------------------------------------------------------
// Reduce partials per (item, scale), then argmin over
// sqrt(s0)+sqrt(s1)+sqrt(s2). 1 block x 1024 threads; wave w (<10) owns
// item w and keeps the three scale ranges separate while summing.
// ---------------------------------------------------------------------------
__global__ void reduce_argmin_kernel(const float* __restrict__ partials,
                                     int* __restrict__ idx_out) {
    __shared__ float tot[10];
    const int wv = threadIdx.x >> 6, lane = threadIdx.x & 63;
    if (wv < 10) {
        const float* p = partials + wv * NBLOCKS;
        float s0 = 0.f, s1 = 0.f, s2 = 0.f;
        for (int i = lane; i < 2048; i += 64) s0 += p[i];
        for (int i = 2048 + lane; i < 3072; i += 64) s1 += p[i];
        for (int i = 3072 + lane; i < 3584; i += 64) s2 += p[i];
        #pragma unroll
        for (int off = 32; off > 0; off >>= 1) {
            s0 += __shfl_down(s0, off);
            s1 += __shfl_down(s1, off);
            s2 += __shfl_down(s2, off);
        }
        if (lane == 0) tot[wv] = sqrtf(s0) + sqrtf(s1) + sqrtf(s2);
    }
    __syncthreads();
    if (threadIdx.x == 0) {
        float best = 3.4e38f; int bi = 0;
        for (int i = 0; i < 10; ++i) {
            float t = tot[i];
            if (t < best) { best = t; bi = i; }
        }
        *idx_out = bi;
    }
}

// ---------------------------------------------------------------------------
// Gather: M[idx] float4 -> CI second half + mi. (Feature half already done.)
// ---------------------------------------------------------------------------
__global__ void gather_kernel(const float* __restrict__ M1, const float* __restrict__ M2,
                              const float* __restrict__ M3, const int* __restrict__ idx_ptr,
                              float* __restrict__ out) {
    const int b = blockIdx.x;
    const float* M; int n4, sh, lb; float* CI; float* mi;
    if (b < 2048)      { M = M1; n4 = 524288; sh = 16; lb = b;        CI = out;           mi = out + 7340032;  }
    else if (b < 3072) { M = M2; n4 = 262144; sh = 15; lb = b - 2048; CI = out + 4194304; mi = out + 9437184;  }
    else               { M = M3; n4 = 131072; sh = 14; lb = b - 3072; CI = out + 6291456; mi = out + 10485760; }
    const int tid = lb * BLK + threadIdx.x;
    const int idx = *idx_ptr;

    float4 v = ((const float4*)M)[(size_t)idx * n4 + tid];
    const int bi = tid >> sh, r = tid & ((1 << sh) - 1);
    const int S4 = 1 << sh;
    ((float4*)CI)[((size_t)bi << (sh + 1)) + S4 + r] = v;
    ((float4*)mi)[tid] = v;
}

extern "C" void kernel_launch(void* const* d_in, const int* in_sizes, int n_in,
                              void* d_out, int out_size, void* d_ws, size_t ws_size,
                              hipStream_t stream) {
    const float* f1 = (const float*)d_in[0];
    const float* f2 = (const float*)d_in[1];
    const float* f3 = (const float*)d_in[2];
    const float* M1 = (const float*)d_in[3];
    const float* M2 = (const float*)d_in[4];
    const float* M3 = (const float*)d_in[5];
    float* out = (float*)d_out;

    // Output flat layout (fp32 elements):
    //   CI1 @ 0         4194304 | CI2 @ 4194304  2097152 | CI3 @ 6291456  1048576
    //   mi1 @ 7340032   2097152 | mi2 @ 9437184  1048576 | mi3 @ 10485760  524288
    // Scratch: partials (10*NBLOCKS fp32 = 143 KB) in the mi3 region (fully
    // overwritten by gather afterwards). idx in d_ws.
    float* partials = out + 10485760;
    int* idxp = (int*)d_ws;

    dist_kernel<<<NBLOCKS, BLK, 0, stream>>>(f1, M1, f2, M2, f3, M3, out, partials);
    reduce_argmin_kernel<<<1, 1024, 0, stream>>>(partials, idxp);
    gather_kernel<<<NBLOCKS, BLK, 0, stream>>>(M1, M2, M3, idxp, out);
}